// Round 7
// baseline (273.281 us; speedup 1.0000x reference)
//
#include <hip/hip_runtime.h>

typedef __bf16 bf16x8 __attribute__((ext_vector_type(8)));
typedef __bf16 bf16x4 __attribute__((ext_vector_type(4)));
typedef float f32x4 __attribute__((ext_vector_type(4)));

typedef const __attribute__((address_space(1))) void* gptr_t;
typedef __attribute__((address_space(3))) void* lptr_t;

__device__ __forceinline__ f32x4 mfma16(bf16x8 a, bf16x8 b, f32x4 c) {
  return __builtin_amdgcn_mfma_f32_16x16x32_bf16(a, b, c, 0, 0, 0);
}

__device__ __forceinline__ void load_lds16(const __bf16* g, __bf16* l) {
  __builtin_amdgcn_global_load_lds((gptr_t)g, (lptr_t)l, 16, 0, 0);
}

__device__ __forceinline__ float fast_exp2(float x) {
#if __has_builtin(__builtin_amdgcn_exp2f)
  return __builtin_amdgcn_exp2f(x);  // raw v_exp_f32
#else
  return exp2f(x);
#endif
}

// round-to-nearest(+away) f32->bf16 for two values, packed into one dword
// (f0 -> low 16 bits, f1 -> high 16 bits)
__device__ __forceinline__ unsigned pack_bf16(float f0, float f1) {
  unsigned u0 = __builtin_bit_cast(unsigned, f0) + 0x8000u;
  unsigned u1 = __builtin_bit_cast(unsigned, f1) + 0x8000u;
  return __builtin_amdgcn_perm(u1, u0, 0x07060302);
}

// ---- fp32 -> bf16 pre-convert: x (4096 blks), qkv_w (1536), out_w (512) ----
__global__ __launch_bounds__(256) void convert3(
    const float* __restrict__ x, const float* __restrict__ w1,
    const float* __restrict__ w2, __bf16* __restrict__ xb,
    __bf16* __restrict__ w1b, __bf16* __restrict__ w2b) {
  int bid = blockIdx.x;
  const float* src;
  __bf16* dst;
  int base;
  if (bid < 4096) {
    src = x; dst = xb; base = bid;
  } else if (bid < 5632) {
    src = w1; dst = w1b; base = bid - 4096;
  } else {
    src = w2; dst = w2b; base = bid - 5632;
  }
  size_t off = (size_t)base * 2048 + threadIdx.x * 8;
  float4 v0 = *(const float4*)(src + off);
  float4 v1 = *(const float4*)(src + off + 4);
  bf16x8 o = {(__bf16)v0.x, (__bf16)v0.y, (__bf16)v0.z, (__bf16)v0.w,
              (__bf16)v1.x, (__bf16)v1.y, (__bf16)v1.z, (__bf16)v1.w};
  *(bf16x8*)(dst + off) = o;
}

// C[M][N] = A[M][K] @ B[N][K]^T + bias[N]; A,B bf16; C bf16 or fp32.
// m97 pattern + chunk-swizzled staging. r7: epilogue reverted to the r0
// scalar-store form (proven fastest: 72.3 us QKV). r6 proved the 50 MB
// overfetch is NOT store-RMW (full-line stores left FETCH unchanged) and
// the 128-shfl butterfly cost +9 us. r0-r3 established this 2-barrier
// structure as the best of 4 schedules on this shape (713 TF).
template <bool C_BF16>
__global__ __launch_bounds__(256) void gemm_bt(
    const __bf16* __restrict__ A, const __bf16* __restrict__ B,
    const float* __restrict__ bias, void* __restrict__ Cv, int M, int N,
    int K, int qcols) {
  __shared__ __bf16 As[2][128 * 32];
  __shared__ __bf16 Bs[2][128 * 32];

  const int tid = threadIdx.x;
  const int wid = tid >> 6;
  const int lane = tid & 63;
  const int l15 = lane & 15;
  const int quad = lane >> 4;
  const int bm = blockIdx.y * 128;
  const int bn = blockIdx.x * 128;
  const int wm = (wid & 1) * 64;
  const int wn = (wid >> 1) * 64;

  // staging: lane l -> row wid*16+(l>>2), global chunk (l&3)^((l>>3)&3)
  const int srow = wid * 16 + (lane >> 2);
  const int schunk = ((lane & 3) ^ ((lane >> 3) & 3)) * 8;
  const __bf16* gA = A + (size_t)(bm + srow) * K + schunk;
  const __bf16* gB = B + (size_t)(bn + srow) * K + schunk;
  const int ldsoff = wid * 16 * 32;  // wave-uniform

  // fragment-read chunk slot (loop-invariant; wm/i*16 vanish mod 4 after >>1)
  const int fsl = (quad ^ ((l15 >> 1) & 3)) * 8;

  f32x4 acc[4][4] = {};

  load_lds16(gA, &As[0][ldsoff]);
  load_lds16(gA + (size_t)64 * K, &As[0][64 * 32 + ldsoff]);
  load_lds16(gB, &Bs[0][ldsoff]);
  load_lds16(gB + (size_t)64 * K, &Bs[0][64 * 32 + ldsoff]);

  const int niter = K >> 5;
  for (int it = 0; it < niter; ++it) {
    const int cur = it & 1;
    __syncthreads();
    if (it + 1 < niter) {
      int k0 = (it + 1) << 5;
      load_lds16(gA + k0, &As[1 - cur][ldsoff]);
      load_lds16(gA + k0 + (size_t)64 * K, &As[1 - cur][64 * 32 + ldsoff]);
      load_lds16(gB + k0, &Bs[1 - cur][ldsoff]);
      load_lds16(gB + k0 + (size_t)64 * K, &Bs[1 - cur][64 * 32 + ldsoff]);
    }
    bf16x8 af[4], bf[4];
#pragma unroll
    for (int i = 0; i < 4; ++i)
      af[i] = *(const bf16x8*)(&As[cur][(wm + i * 16 + l15) * 32 + fsl]);
#pragma unroll
    for (int i = 0; i < 4; ++i)
      bf[i] = *(const bf16x8*)(&Bs[cur][(wn + i * 16 + l15) * 32 + fsl]);
#pragma unroll
    for (int mt = 0; mt < 4; ++mt)
#pragma unroll
      for (int nt = 0; nt < 4; ++nt)
        acc[mt][nt] = mfma16(af[mt], bf[nt], acc[mt][nt]);
  }

  const float sc = (bn < qcols) ? 0.18033688011112043f : 1.0f;
#pragma unroll
  for (int mt = 0; mt < 4; ++mt) {
#pragma unroll
    for (int nt = 0; nt < 4; ++nt) {
      int gc = bn + wn + nt * 16 + l15;
      float bv = bias[gc];
#pragma unroll
      for (int r = 0; r < 4; ++r) {
        int gr = bm + wm + mt * 16 + quad * 4 + r;
        float val = (acc[mt][nt][r] + bv) * sc;
        if constexpr (C_BF16)
          ((__bf16*)Cv)[(size_t)gr * N + gc] = (__bf16)val;
        else
          ((float*)Cv)[(size_t)gr * N + gc] = val;
      }
    }
  }
}

// exp + (optional causal mask) + deferred-l + packed P store in pi-layout.
template <bool MASK>
__device__ __forceinline__ void softmax_block(f32x4 (&s)[2][4],
                                              float (&lsum)[2][4],
                                              __bf16* __restrict__ psw,
                                              int kv0, int qrow_base, int quad,
                                              int l15) {
#pragma unroll
  for (int mt = 0; mt < 2; ++mt) {
#pragma unroll
    for (int r = 0; r < 4; ++r) {
      int prow = mt * 16 + quad * 4 + r;
      float p[4];
#pragma unroll
      for (int nt = 0; nt < 4; ++nt) {
        p[nt] = fast_exp2(s[mt][nt][r]);  // scale pre-folded into Q
        if constexpr (MASK) {
          if ((kv0 + nt * 16 + l15) > (qrow_base + prow)) p[nt] = 0.f;
        }
      }
      lsum[mt][r] += (p[0] + p[1]) + (p[2] + p[3]);
      uint2 w = {pack_bf16(p[0], p[1]), pack_bf16(p[2], p[3])};
      int o = ((l15 >> 1) ^ (prow & 7)) & 7;
      *(uint2*)(psw + prow * 64 + o * 8 + 4 * (l15 & 1)) = w;
    }
  }
}

// Flash attention, causal. qkv: (B*T, 3072) bf16 (Q pre-scaled by log2e/8);
// out: (B*T, 1024) bf16. Grid (64 bh, 8 pb) bh-fastest. Block 256 = 4 waves,
// BQ=128, BKV=64; phases {pb, 15-pb} -> 34 tiles/block.
// r7: WRITE-BEHIND KV pipeline. Old: per tile {ds_write K/V; prefetch;
// barrier; compute} put the staging writes' lgkm drain on the barrier
// critical path every tile. New: per tile j {QK(j) from buf j&1;
// ds_write tile j+1 -> buf (j+1)&1 (regs loaded at iter j-1);
// issue global loads of tile j+2; softmax; PV(j); barrier}. Staging now
// overlaps MFMA/softmax; barrier count unchanged (1/tile).
// Hazards: write to buf (j+1)&1 occurs after the barrier that closed its
// last reader (iter j-1); its readers run after this body's closing
// barrier; reg slots re-issued only after their ds_write, >=1 tile body
// (~900 cyc) of vmcnt cover. ntiles = 2qp+2 is always EVEN -> 2-tile
// unrolled pairs make buffer/reg parities compile-time (rule #20).
// T5 setprio on both MFMA clusters (kept; ~-3 us with the cheap 32-shfl
// full-line out-store, r6 subtraction).
__global__ __launch_bounds__(256) void attn_kernel(
    const __bf16* __restrict__ qkv, __bf16* __restrict__ out) {
  constexpr int T = 2048, C3 = 3072;
  constexpr int KVSTEP = 64 * C3;
  __shared__ __bf16 Ks[2][64 * 64];  // [kv][d]
  __shared__ __bf16 Vt[2][64 * 64];  // [d][pi(kv)]
  __shared__ __bf16 Ps[4][32 * 64];  // per-wave [qrow][pi(kv)]

  const int tid = threadIdx.x;
  const int wid = tid >> 6;
  const int lane = tid & 63;
  const int l15 = lane & 15;
  const int quad = lane >> 4;
  const int bh = blockIdx.x;  // 0..63 (fastest -> same XCD per bh)
  const int pb = blockIdx.y;  // 0..7
  const int b = bh >> 4, h = bh & 15;
  const size_t rowbase = (size_t)b * T;

  const int kr = tid >> 3;  // K staging: rows kr, kr+32
  const int kc = tid & 7;   // d-octet
  const int vj = tid >> 4;  // V staging: rows vj+16i -> pi-cols 4vj+i
  const int vn = tid & 15;  // d-nibble

  const __bf16* gk_base = qkv + rowbase * C3 + 1024 + h * 64 + kr * C3 + kc * 8;
  const __bf16* gv_base = qkv + rowbase * C3 + 2048 + h * 64 + vj * C3 + vn * 4;

  // ---- loop-invariant LDS offsets (elements) ----
  int ks_st0 = kr * 64 + ((kc ^ (kr & 7)) * 8);            // K store row kr
  int ks_st1 = (kr + 32) * 64 + ((kc ^ ((kr + 32) & 7)) * 8);
  int vt_st[4];
#pragma unroll
  for (int dd = 0; dd < 4; ++dd) {
    int d = 4 * vn + dd;
    vt_st[dd] = d * 64 + ((((vj >> 1) ^ (d & 7) ^ (d >> 3)) & 7) * 8) +
                4 * (vj & 1);
  }
  int kf_off[4][2];
#pragma unroll
  for (int nt = 0; nt < 4; ++nt)
#pragma unroll
    for (int ksi = 0; ksi < 2; ++ksi)
      kf_off[nt][ksi] =
          (nt * 16 + l15) * 64 + (((4 * ksi + quad) ^ (l15 & 7)) * 8);
  int pf_off[2][2];
#pragma unroll
  for (int mt = 0; mt < 2; ++mt)
#pragma unroll
    for (int ksi = 0; ksi < 2; ++ksi)
      pf_off[mt][ksi] =
          (mt * 16 + l15) * 64 + (((4 * ksi + quad) ^ (l15 & 7)) * 8);
  int vf_off[4][2];
#pragma unroll
  for (int ntv = 0; ntv < 4; ++ntv)
#pragma unroll
    for (int ksi = 0; ksi < 2; ++ksi) {
      int d = ntv * 16 + l15;
      vf_off[ntv][ksi] =
          d * 64 + ((((4 * ksi + quad) ^ (d & 7) ^ (d >> 3)) & 7) * 8);
    }

// One KV-tile body. BUF: compile-time LDS buffer parity of tile J.
// WK/WV: registers holding tile J+1 (written behind QK). LK/LV: register
// slot to receive tile J+2's global loads.
#define KV_TILE(J, BUF, WK, WV, LK, LV)                                       \
  {                                                                           \
    const int kv0 = (J) * 64;                                                 \
    __bf16* ksb = Ks[BUF];                                                    \
    __bf16* vtb = Vt[BUF];                                                    \
    f32x4 s[2][4] = {};                                                       \
    __builtin_amdgcn_s_setprio(1);                                            \
    _Pragma("unroll") for (int nt = 0; nt < 4; ++nt) {                        \
      _Pragma("unroll") for (int ksi = 0; ksi < 2; ++ksi) {                   \
        bf16x8 kf = *(const bf16x8*)(ksb + kf_off[nt][ksi]);                  \
        _Pragma("unroll") for (int mt = 0; mt < 2; ++mt) s[mt][nt] =          \
            mfma16(qf[mt][ksi], kf, s[mt][nt]);                               \
      }                                                                       \
    }                                                                         \
    __builtin_amdgcn_s_setprio(0);                                            \
    if ((J) + 1 < ntiles) { /* write-behind: stage tile J+1 */                \
      __bf16* ksn = Ks[1 - (BUF)];                                            \
      __bf16* vtn = Vt[1 - (BUF)];                                            \
      *(bf16x8*)(ksn + ks_st0) = WK[0];                                       \
      *(bf16x8*)(ksn + ks_st1) = WK[1];                                       \
      _Pragma("unroll") for (int dd = 0; dd < 4; ++dd) {                      \
        bf16x4 t = {WV[0][dd], WV[1][dd], WV[2][dd], WV[3][dd]};              \
        *(bf16x4*)(vtn + vt_st[dd]) = t;                                      \
      }                                                                       \
    }                                                                         \
    if ((J) + 2 < ntiles) { /* issue tile J+2 global loads */                 \
      const __bf16* gnk = gk_base + (size_t)((J) + 2) * KVSTEP;               \
      const __bf16* gnv = gv_base + (size_t)((J) + 2) * KVSTEP;               \
      LK[0] = *(const bf16x8*)(gnk);                                          \
      LK[1] = *(const bf16x8*)(gnk + 32 * C3);                                \
      _Pragma("unroll") for (int i = 0; i < 4; ++i) LV[i] =                   \
          *(const bf16x4*)(gnv + (size_t)i * 16 * C3);                        \
    }                                                                         \
    if ((kv0 + 63) > qrow_base)                                               \
      softmax_block<true>(s, lsum, Ps[wid], kv0, qrow_base, quad, l15);       \
    else                                                                      \
      softmax_block<false>(s, lsum, Ps[wid], kv0, qrow_base, quad, l15);      \
    __builtin_amdgcn_s_setprio(1);                                            \
    _Pragma("unroll") for (int ksi = 0; ksi < 2; ++ksi) {                     \
      bf16x8 pf[2];                                                           \
      _Pragma("unroll") for (int mt = 0; mt < 2; ++mt) pf[mt] =               \
          *(const bf16x8*)(Ps[wid] + pf_off[mt][ksi]);                        \
      _Pragma("unroll") for (int ntv = 0; ntv < 4; ++ntv) {                   \
        bf16x8 vf = *(const bf16x8*)(vtb + vf_off[ntv][ksi]);                 \
        _Pragma("unroll") for (int mt = 0; mt < 2; ++mt) acc[mt][ntv] =       \
            mfma16(pf[mt], vf, acc[mt][ntv]);                                 \
      }                                                                       \
    }                                                                         \
    __builtin_amdgcn_s_setprio(0);                                            \
    __syncthreads();                                                          \
  }

#pragma unroll 1
  for (int phase = 0; phase < 2; ++phase) {
    const int qp = phase == 0 ? pb : 15 - pb;
    const int q0 = qp * 128;
    const int ntiles = 2 * qp + 2;  // always even, >= 2
    const int qrow_base = q0 + wid * 32;

    bf16x8 qf[2][2];
#pragma unroll
    for (int mt = 0; mt < 2; ++mt)
#pragma unroll
      for (int ksi = 0; ksi < 2; ++ksi)
        qf[mt][ksi] = *(const bf16x8*)(
            qkv + (rowbase + qrow_base + mt * 16 + l15) * C3 + h * 64 +
            ksi * 32 + quad * 8);

    f32x4 acc[2][4] = {};
    float lsum[2][4] = {};

    // prologue: tiles 0 and 1 into registers (ntiles >= 2 always)
    bf16x8 kA[2], kB[2];
    bf16x4 vA[4], vB[4];
    kA[0] = *(const bf16x8*)(gk_base);
    kA[1] = *(const bf16x8*)(gk_base + 32 * C3);
#pragma unroll
    for (int i = 0; i < 4; ++i)
      vA[i] = *(const bf16x4*)(gv_base + (size_t)i * 16 * C3);
    kB[0] = *(const bf16x8*)(gk_base + KVSTEP);
    kB[1] = *(const bf16x8*)(gk_base + KVSTEP + 32 * C3);
#pragma unroll
    for (int i = 0; i < 4; ++i)
      vB[i] = *(const bf16x4*)(gv_base + KVSTEP + (size_t)i * 16 * C3);

    __syncthreads();  // previous phase's readers done

    // stage tile 0 (from A-regs); A-slot becomes free for tile 2
    *(bf16x8*)(Ks[0] + ks_st0) = kA[0];
    *(bf16x8*)(Ks[0] + ks_st1) = kA[1];
#pragma unroll
    for (int dd = 0; dd < 4; ++dd) {
      bf16x4 t = {vA[0][dd], vA[1][dd], vA[2][dd], vA[3][dd]};
      *(bf16x4*)(Vt[0] + vt_st[dd]) = t;
    }
    __syncthreads();  // tile 0 visible

    for (int jj = 0; jj < ntiles; jj += 2) {
      KV_TILE(jj, 0, kB, vB, kA, vA);      // write tile jj+1; issue jj+2 -> A
      KV_TILE(jj + 1, 1, kA, vA, kB, vB);  // write tile jj+2; issue jj+3 -> B
    }

    // ---- phase epilogue: reduce l, normalize, packed full-line store ----
    const int srcl = (lane & 48) + ((2 * l15) & 15);
#pragma unroll
    for (int mt = 0; mt < 2; ++mt)
#pragma unroll
      for (int r = 0; r < 4; ++r) {
        float l = lsum[mt][r];
        l += __shfl_xor(l, 1);
        l += __shfl_xor(l, 2);
        l += __shfl_xor(l, 4);
        l += __shfl_xor(l, 8);
        float inv = 1.0f / l;  // uniform within the 16-lane group
        int row = qrow_base + mt * 16 + quad * 4 + r;
        size_t ob = (rowbase + row) * 1024 + h * 64;
#pragma unroll
        for (int np = 0; np < 2; ++np) {
          float a0 = acc[mt][2 * np][r] * inv;      // tile n0, col l15
          float a1 = acc[mt][2 * np + 1][r] * inv;  // tile n1, col l15
          float t0 = __shfl(a0, srcl);
          float t1 = __shfl(a1, srcl);
          float u0 = __shfl(a0, srcl + 1);
          float u1 = __shfl(a1, srcl + 1);
          float lo = (l15 < 8) ? t0 : t1;  // strip col 2*l15
          float hi = (l15 < 8) ? u0 : u1;  // strip col 2*l15+1
          *(unsigned*)(out + ob + np * 32 + 2 * l15) = pack_bf16(lo, hi);
        }
      }
  }
#undef KV_TILE
}

extern "C" void kernel_launch(void* const* d_in, const int* in_sizes, int n_in,
                              void* d_out, int out_size, void* d_ws,
                              size_t ws_size, hipStream_t stream) {
  const float* x = (const float*)d_in[0];
  const float* qkv_w = (const float*)d_in[1];
  const float* qkv_b = (const float*)d_in[2];
  const float* out_w = (const float*)d_in[3];
  const float* out_b = (const float*)d_in[4];
  float* out = (float*)d_out;

  __bf16* qkv_ws = (__bf16*)d_ws;                  // 8192*3072
  __bf16* attn_ws = qkv_ws + (size_t)8192 * 3072;  // 8192*1024
  __bf16* xb = attn_ws + (size_t)8192 * 1024;      // 8192*1024
  __bf16* wqb = xb + (size_t)8192 * 1024;          // 3072*1024
  __bf16* wob = wqb + (size_t)3072 * 1024;         // 1024*1024

  convert3<<<6144, 256, 0, stream>>>(x, qkv_w, out_w, xb, wqb, wob);
  gemm_bt<true><<<dim3(24, 64), 256, 0, stream>>>(xb, wqb, qkv_b, qkv_ws,
                                                  8192, 3072, 1024, 1024);
  attn_kernel<<<dim3(64, 8), 256, 0, stream>>>(qkv_ws, attn_ws);
  gemm_bt<false><<<dim3(8, 64), 256, 0, stream>>>(attn_ws, wob, out_b, out,
                                                  8192, 1024, 1024, 0);
}

// Round 8
// 258.603 us; speedup vs baseline: 1.0568x; 1.0568x over previous
//
#include <hip/hip_runtime.h>

typedef __bf16 bf16x8 __attribute__((ext_vector_type(8)));
typedef __bf16 bf16x4 __attribute__((ext_vector_type(4)));
typedef float f32x4 __attribute__((ext_vector_type(4)));

typedef const __attribute__((address_space(1))) void* gptr_t;
typedef __attribute__((address_space(3))) void* lptr_t;

__device__ __forceinline__ f32x4 mfma16(bf16x8 a, bf16x8 b, f32x4 c) {
  return __builtin_amdgcn_mfma_f32_16x16x32_bf16(a, b, c, 0, 0, 0);
}

__device__ __forceinline__ void load_lds16(const __bf16* g, __bf16* l) {
  __builtin_amdgcn_global_load_lds((gptr_t)g, (lptr_t)l, 16, 0, 0);
}

__device__ __forceinline__ float fast_exp2(float x) {
#if __has_builtin(__builtin_amdgcn_exp2f)
  return __builtin_amdgcn_exp2f(x);  // raw v_exp_f32
#else
  return exp2f(x);
#endif
}

// round-to-nearest(+away) f32->bf16 for two values, packed into one dword
// (f0 -> low 16 bits, f1 -> high 16 bits)
__device__ __forceinline__ unsigned pack_bf16(float f0, float f1) {
  unsigned u0 = __builtin_bit_cast(unsigned, f0) + 0x8000u;
  unsigned u1 = __builtin_bit_cast(unsigned, f1) + 0x8000u;
  return __builtin_amdgcn_perm(u1, u0, 0x07060302);
}

// ---- fp32 -> bf16 pre-convert: x (4096 blks), qkv_w (1536), out_w (512) ----
__global__ __launch_bounds__(256) void convert3(
    const float* __restrict__ x, const float* __restrict__ w1,
    const float* __restrict__ w2, __bf16* __restrict__ xb,
    __bf16* __restrict__ w1b, __bf16* __restrict__ w2b) {
  int bid = blockIdx.x;
  const float* src;
  __bf16* dst;
  int base;
  if (bid < 4096) {
    src = x; dst = xb; base = bid;
  } else if (bid < 5632) {
    src = w1; dst = w1b; base = bid - 4096;
  } else {
    src = w2; dst = w2b; base = bid - 5632;
  }
  size_t off = (size_t)base * 2048 + threadIdx.x * 8;
  float4 v0 = *(const float4*)(src + off);
  float4 v1 = *(const float4*)(src + off + 4);
  bf16x8 o = {(__bf16)v0.x, (__bf16)v0.y, (__bf16)v0.z, (__bf16)v0.w,
              (__bf16)v1.x, (__bf16)v1.y, (__bf16)v1.z, (__bf16)v1.w};
  *(bf16x8*)(dst + off) = o;
}

// C[M][N] = A[M][K] @ B[N][K]^T + bias[N]; A,B bf16; C bf16 or fp32.
// EXACT r0 structure (best measured: QKV 72.3 us / 713 TF). r0-r7 session
// evidence: 8-phase/ring-4 schedules null (r1-r3), T1 XCD swizzle negative
// at 18% HBM (r4), butterfly full-line epilogue negative (r6, and proved
// the 50 MB overfetch is NOT store-RMW). Keep as-is.
template <bool C_BF16>
__global__ __launch_bounds__(256) void gemm_bt(
    const __bf16* __restrict__ A, const __bf16* __restrict__ B,
    const float* __restrict__ bias, void* __restrict__ Cv, int M, int N,
    int K, int qcols) {
  __shared__ __bf16 As[2][128 * 32];
  __shared__ __bf16 Bs[2][128 * 32];

  const int tid = threadIdx.x;
  const int wid = tid >> 6;
  const int lane = tid & 63;
  const int l15 = lane & 15;
  const int quad = lane >> 4;
  const int bm = blockIdx.y * 128;
  const int bn = blockIdx.x * 128;
  const int wm = (wid & 1) * 64;
  const int wn = (wid >> 1) * 64;

  // staging: lane l -> row wid*16+(l>>2), global chunk (l&3)^((l>>3)&3)
  const int srow = wid * 16 + (lane >> 2);
  const int schunk = ((lane & 3) ^ ((lane >> 3) & 3)) * 8;
  const __bf16* gA = A + (size_t)(bm + srow) * K + schunk;
  const __bf16* gB = B + (size_t)(bn + srow) * K + schunk;
  const int ldsoff = wid * 16 * 32;  // wave-uniform

  // fragment-read chunk slot (loop-invariant; wm/i*16 vanish mod 4 after >>1)
  const int fsl = (quad ^ ((l15 >> 1) & 3)) * 8;

  f32x4 acc[4][4] = {};

  load_lds16(gA, &As[0][ldsoff]);
  load_lds16(gA + (size_t)64 * K, &As[0][64 * 32 + ldsoff]);
  load_lds16(gB, &Bs[0][ldsoff]);
  load_lds16(gB + (size_t)64 * K, &Bs[0][64 * 32 + ldsoff]);

  const int niter = K >> 5;
  for (int it = 0; it < niter; ++it) {
    const int cur = it & 1;
    __syncthreads();
    if (it + 1 < niter) {
      int k0 = (it + 1) << 5;
      load_lds16(gA + k0, &As[1 - cur][ldsoff]);
      load_lds16(gA + k0 + (size_t)64 * K, &As[1 - cur][64 * 32 + ldsoff]);
      load_lds16(gB + k0, &Bs[1 - cur][ldsoff]);
      load_lds16(gB + k0 + (size_t)64 * K, &Bs[1 - cur][64 * 32 + ldsoff]);
    }
    bf16x8 af[4], bf[4];
#pragma unroll
    for (int i = 0; i < 4; ++i)
      af[i] = *(const bf16x8*)(&As[cur][(wm + i * 16 + l15) * 32 + fsl]);
#pragma unroll
    for (int i = 0; i < 4; ++i)
      bf[i] = *(const bf16x8*)(&Bs[cur][(wn + i * 16 + l15) * 32 + fsl]);
#pragma unroll
    for (int mt = 0; mt < 4; ++mt)
#pragma unroll
      for (int nt = 0; nt < 4; ++nt)
        acc[mt][nt] = mfma16(af[mt], bf[nt], acc[mt][nt]);
  }

  const float sc = (bn < qcols) ? 0.18033688011112043f : 1.0f;
#pragma unroll
  for (int mt = 0; mt < 4; ++mt) {
#pragma unroll
    for (int nt = 0; nt < 4; ++nt) {
      int gc = bn + wn + nt * 16 + l15;
      float bv = bias[gc];
#pragma unroll
      for (int r = 0; r < 4; ++r) {
        int gr = bm + wm + mt * 16 + quad * 4 + r;
        float val = (acc[mt][nt][r] + bv) * sc;
        if constexpr (C_BF16)
          ((__bf16*)Cv)[(size_t)gr * N + gc] = (__bf16)val;
        else
          ((float*)Cv)[(size_t)gr * N + gc] = val;
      }
    }
  }
}

// exp + (optional causal mask) + deferred-l + packed P store in pi-layout.
template <bool MASK>
__device__ __forceinline__ void softmax_block(f32x4 (&s)[2][4],
                                              float (&lsum)[2][4],
                                              __bf16* __restrict__ psw,
                                              int kv0, int qrow_base, int quad,
                                              int l15) {
#pragma unroll
  for (int mt = 0; mt < 2; ++mt) {
#pragma unroll
    for (int r = 0; r < 4; ++r) {
      int prow = mt * 16 + quad * 4 + r;
      float p[4];
#pragma unroll
      for (int nt = 0; nt < 4; ++nt) {
        p[nt] = fast_exp2(s[mt][nt][r]);  // scale pre-folded into Q
        if constexpr (MASK) {
          if ((kv0 + nt * 16 + l15) > (qrow_base + prow)) p[nt] = 0.f;
        }
      }
      lsum[mt][r] += (p[0] + p[1]) + (p[2] + p[3]);
      uint2 w = {pack_bf16(p[0], p[1]), pack_bf16(p[2], p[3])};
      int o = ((l15 >> 1) ^ (prow & 7)) & 7;
      *(uint2*)(psw + prow * 64 + o * 8 + 4 * (l15 & 1)) = w;
    }
  }
}

// Flash attention, causal. qkv: (B*T, 3072) bf16 (Q pre-scaled by log2e/8);
// out: (B*T, 1024) bf16. Grid (64 bh, 8 pb) bh-fastest. Block 256 = 4 waves,
// BQ=128, BKV=64; phases {pb, 15-pb} -> 34 tiles/block.
// EXACT r6 attn (best measured attn config, ~-3.7 us vs r0 attn by
// subtraction): classic staging loop {ds_write K/V; prefetch regs; barrier;
// compute}, T5 setprio on both MFMA clusters, packed full-line out-store
// (cheap 32-shfl butterfly). r7's write-behind restructure REGRESSED
// (VGPR 120->156, occupancy 10.9%, 3.3M bank conflicts, 112 us) — reverted.
__global__ __launch_bounds__(256) void attn_kernel(
    const __bf16* __restrict__ qkv, __bf16* __restrict__ out) {
  constexpr int T = 2048, C3 = 3072;
  constexpr int KVSTEP = 64 * C3;
  __shared__ __bf16 Ks[2][64 * 64];  // [kv][d]
  __shared__ __bf16 Vt[2][64 * 64];  // [d][pi(kv)]
  __shared__ __bf16 Ps[4][32 * 64];  // per-wave [qrow][pi(kv)]

  const int tid = threadIdx.x;
  const int wid = tid >> 6;
  const int lane = tid & 63;
  const int l15 = lane & 15;
  const int quad = lane >> 4;
  const int bh = blockIdx.x;  // 0..63 (fastest -> same XCD per bh)
  const int pb = blockIdx.y;  // 0..7
  const int b = bh >> 4, h = bh & 15;
  const size_t rowbase = (size_t)b * T;

  const int kr = tid >> 3;  // K staging: rows kr, kr+32
  const int kc = tid & 7;   // d-octet
  const int vj = tid >> 4;  // V staging: rows vj+16i -> pi-cols 4vj+i
  const int vn = tid & 15;  // d-nibble

  const __bf16* gk_base = qkv + rowbase * C3 + 1024 + h * 64 + kr * C3 + kc * 8;
  const __bf16* gv_base = qkv + rowbase * C3 + 2048 + h * 64 + vj * C3 + vn * 4;

  // ---- loop-invariant LDS offsets (elements) ----
  int ks_st0 = kr * 64 + ((kc ^ (kr & 7)) * 8);            // K store row kr
  int ks_st1 = (kr + 32) * 64 + ((kc ^ ((kr + 32) & 7)) * 8);
  int vt_st[4];
#pragma unroll
  for (int dd = 0; dd < 4; ++dd) {
    int d = 4 * vn + dd;
    vt_st[dd] = d * 64 + ((((vj >> 1) ^ (d & 7) ^ (d >> 3)) & 7) * 8) +
                4 * (vj & 1);
  }
  int kf_off[4][2];
#pragma unroll
  for (int nt = 0; nt < 4; ++nt)
#pragma unroll
    for (int ksi = 0; ksi < 2; ++ksi)
      kf_off[nt][ksi] =
          (nt * 16 + l15) * 64 + (((4 * ksi + quad) ^ (l15 & 7)) * 8);
  int pf_off[2][2];
#pragma unroll
  for (int mt = 0; mt < 2; ++mt)
#pragma unroll
    for (int ksi = 0; ksi < 2; ++ksi)
      pf_off[mt][ksi] =
          (mt * 16 + l15) * 64 + (((4 * ksi + quad) ^ (l15 & 7)) * 8);
  int vf_off[4][2];
#pragma unroll
  for (int ntv = 0; ntv < 4; ++ntv)
#pragma unroll
    for (int ksi = 0; ksi < 2; ++ksi) {
      int d = ntv * 16 + l15;
      vf_off[ntv][ksi] =
          d * 64 + ((((4 * ksi + quad) ^ (d & 7) ^ (d >> 3)) & 7) * 8);
    }

#pragma unroll 1
  for (int phase = 0; phase < 2; ++phase) {
    const int qp = phase == 0 ? pb : 15 - pb;
    const int q0 = qp * 128;
    const int ntiles = 2 * qp + 2;
    const int qrow_base = q0 + wid * 32;

    bf16x8 qf[2][2];
#pragma unroll
    for (int mt = 0; mt < 2; ++mt)
#pragma unroll
      for (int ksi = 0; ksi < 2; ++ksi)
        qf[mt][ksi] = *(const bf16x8*)(
            qkv + (rowbase + qrow_base + mt * 16 + l15) * C3 + h * 64 +
            ksi * 32 + quad * 8);

    f32x4 acc[2][4] = {};
    float lsum[2][4] = {};

    const __bf16* gk = gk_base;
    const __bf16* gv = gv_base;

    bf16x8 kreg[2];
    bf16x4 vreg[4];
    kreg[0] = *(const bf16x8*)(gk);
    kreg[1] = *(const bf16x8*)(gk + 32 * C3);
#pragma unroll
    for (int i = 0; i < 4; ++i)
      vreg[i] = *(const bf16x4*)(gv + i * 16 * C3);

    __syncthreads();  // previous phase's readers done

    for (int j = 0; j < ntiles; ++j) {
      __bf16* ksb = Ks[j & 1];
      __bf16* vtb = Vt[j & 1];
      *(bf16x8*)(ksb + ks_st0) = kreg[0];
      *(bf16x8*)(ksb + ks_st1) = kreg[1];
#pragma unroll
      for (int dd = 0; dd < 4; ++dd) {
        bf16x4 t = {vreg[0][dd], vreg[1][dd], vreg[2][dd], vreg[3][dd]};
        *(bf16x4*)(vtb + vt_st[dd]) = t;
      }
      if (j + 1 < ntiles) {
        gk += KVSTEP;
        gv += KVSTEP;
        kreg[0] = *(const bf16x8*)(gk);
        kreg[1] = *(const bf16x8*)(gk + 32 * C3);
#pragma unroll
        for (int i = 0; i < 4; ++i)
          vreg[i] = *(const bf16x4*)(gv + i * 16 * C3);
      }
      __syncthreads();

      const int kv0 = j * 64;
      // ---- S = Q K^T ----
      f32x4 s[2][4] = {};
      __builtin_amdgcn_s_setprio(1);
#pragma unroll
      for (int nt = 0; nt < 4; ++nt) {
#pragma unroll
        for (int ksi = 0; ksi < 2; ++ksi) {
          bf16x8 kf = *(const bf16x8*)(ksb + kf_off[nt][ksi]);
#pragma unroll
          for (int mt = 0; mt < 2; ++mt)
            s[mt][nt] = mfma16(qf[mt][ksi], kf, s[mt][nt]);
        }
      }
      __builtin_amdgcn_s_setprio(0);
      // ---- softmax (wave-uniform mask branch) ----
      if ((kv0 + 63) > qrow_base)
        softmax_block<true>(s, lsum, Ps[wid], kv0, qrow_base, quad, l15);
      else
        softmax_block<false>(s, lsum, Ps[wid], kv0, qrow_base, quad, l15);

      // ---- O += P V (per-wave Ps: no barrier) ----
      __builtin_amdgcn_s_setprio(1);
#pragma unroll
      for (int ksi = 0; ksi < 2; ++ksi) {
        bf16x8 pf[2];
#pragma unroll
        for (int mt = 0; mt < 2; ++mt)
          pf[mt] = *(const bf16x8*)(Ps[wid] + pf_off[mt][ksi]);
#pragma unroll
        for (int ntv = 0; ntv < 4; ++ntv) {
          bf16x8 vf = *(const bf16x8*)(vtb + vf_off[ntv][ksi]);
#pragma unroll
          for (int mt = 0; mt < 2; ++mt)
            acc[mt][ntv] = mfma16(pf[mt], vf, acc[mt][ntv]);
        }
      }
      __builtin_amdgcn_s_setprio(0);
    }

    // ---- phase epilogue: reduce l, normalize, packed full-line store ----
    const int srcl = (lane & 48) + ((2 * l15) & 15);
#pragma unroll
    for (int mt = 0; mt < 2; ++mt)
#pragma unroll
      for (int r = 0; r < 4; ++r) {
        float l = lsum[mt][r];
        l += __shfl_xor(l, 1);
        l += __shfl_xor(l, 2);
        l += __shfl_xor(l, 4);
        l += __shfl_xor(l, 8);
        float inv = 1.0f / l;  // uniform within the 16-lane group
        int row = qrow_base + mt * 16 + quad * 4 + r;
        size_t ob = (rowbase + row) * 1024 + h * 64;
#pragma unroll
        for (int np = 0; np < 2; ++np) {
          float a0 = acc[mt][2 * np][r] * inv;      // tile n0, col l15
          float a1 = acc[mt][2 * np + 1][r] * inv;  // tile n1, col l15
          float t0 = __shfl(a0, srcl);
          float t1 = __shfl(a1, srcl);
          float u0 = __shfl(a0, srcl + 1);
          float u1 = __shfl(a1, srcl + 1);
          float lo = (l15 < 8) ? t0 : t1;  // strip col 2*l15
          float hi = (l15 < 8) ? u0 : u1;  // strip col 2*l15+1
          *(unsigned*)(out + ob + np * 32 + 2 * l15) = pack_bf16(lo, hi);
        }
      }
  }
}

extern "C" void kernel_launch(void* const* d_in, const int* in_sizes, int n_in,
                              void* d_out, int out_size, void* d_ws,
                              size_t ws_size, hipStream_t stream) {
  const float* x = (const float*)d_in[0];
  const float* qkv_w = (const float*)d_in[1];
  const float* qkv_b = (const float*)d_in[2];
  const float* out_w = (const float*)d_in[3];
  const float* out_b = (const float*)d_in[4];
  float* out = (float*)d_out;

  __bf16* qkv_ws = (__bf16*)d_ws;                  // 8192*3072
  __bf16* attn_ws = qkv_ws + (size_t)8192 * 3072;  // 8192*1024
  __bf16* xb = attn_ws + (size_t)8192 * 1024;      // 8192*1024
  __bf16* wqb = xb + (size_t)8192 * 1024;          // 3072*1024
  __bf16* wob = wqb + (size_t)3072 * 1024;         // 1024*1024

  convert3<<<6144, 256, 0, stream>>>(x, qkv_w, out_w, xb, wqb, wob);
  gemm_bt<true><<<dim3(24, 64), 256, 0, stream>>>(xb, wqb, qkv_b, qkv_ws,
                                                  8192, 3072, 1024, 1024);
  attn_kernel<<<dim3(64, 8), 256, 0, stream>>>(qkv_ws, attn_ws);
  gemm_bt<false><<<dim3(8, 64), 256, 0, stream>>>(attn_ws, wob, out_b, out,
                                                  8192, 1024, 1024, 0);
}

// Round 9
// 242.596 us; speedup vs baseline: 1.1265x; 1.0660x over previous
//
#include <hip/hip_runtime.h>

typedef __bf16 bf16x8 __attribute__((ext_vector_type(8)));
typedef __bf16 bf16x4 __attribute__((ext_vector_type(4)));
typedef float f32x4 __attribute__((ext_vector_type(4)));

typedef const __attribute__((address_space(1))) void* gptr_t;
typedef __attribute__((address_space(3))) void* lptr_t;

__device__ __forceinline__ f32x4 mfma16(bf16x8 a, bf16x8 b, f32x4 c) {
  return __builtin_amdgcn_mfma_f32_16x16x32_bf16(a, b, c, 0, 0, 0);
}

__device__ __forceinline__ void load_lds16(const __bf16* g, __bf16* l) {
  __builtin_amdgcn_global_load_lds((gptr_t)g, (lptr_t)l, 16, 0, 0);
}

__device__ __forceinline__ float fast_exp2(float x) {
#if __has_builtin(__builtin_amdgcn_exp2f)
  return __builtin_amdgcn_exp2f(x);  // raw v_exp_f32
#else
  return exp2f(x);
#endif
}

// round-to-nearest(+away) f32->bf16 for two values, packed into one dword
__device__ __forceinline__ unsigned pack_bf16(float f0, float f1) {
  unsigned u0 = __builtin_bit_cast(unsigned, f0) + 0x8000u;
  unsigned u1 = __builtin_bit_cast(unsigned, f1) + 0x8000u;
  return __builtin_amdgcn_perm(u1, u0, 0x07060302);
}

// ---- fp32 -> bf16 pre-convert: x (4096 blks), qkv_w (1536), out_w (512) ----
__global__ __launch_bounds__(256) void convert3(
    const float* __restrict__ x, const float* __restrict__ w1,
    const float* __restrict__ w2, __bf16* __restrict__ xb,
    __bf16* __restrict__ w1b, __bf16* __restrict__ w2b) {
  int bid = blockIdx.x;
  const float* src;
  __bf16* dst;
  int base;
  if (bid < 4096) {
    src = x; dst = xb; base = bid;
  } else if (bid < 5632) {
    src = w1; dst = w1b; base = bid - 4096;
  } else {
    src = w2; dst = w2b; base = bid - 5632;
  }
  size_t off = (size_t)base * 2048 + threadIdx.x * 8;
  float4 v0 = *(const float4*)(src + off);
  float4 v1 = *(const float4*)(src + off + 4);
  bf16x8 o = {(__bf16)v0.x, (__bf16)v0.y, (__bf16)v0.z, (__bf16)v0.w,
              (__bf16)v1.x, (__bf16)v1.y, (__bf16)v1.z, (__bf16)v1.w};
  *(bf16x8*)(dst + off) = o;
}

// C[M][N] = A[M][K] @ B[N][K]^T + bias[N]; A,B bf16; C bf16 or fp32.
// EXACT r0 structure (best measured: QKV 72.3 us, 713 TF, stable across
// 3 independent runs). Session evidence: 8-phase/ring-4 schedules null
// (r1-r3), T1 XCD swizzle negative at 18% HBM (r4), butterfly full-line
// epilogue negative (r6; also proved the 50 MB overfetch is not store-RMW).
template <bool C_BF16>
__global__ __launch_bounds__(256) void gemm_bt(
    const __bf16* __restrict__ A, const __bf16* __restrict__ B,
    const float* __restrict__ bias, void* __restrict__ Cv, int M, int N,
    int K, int qcols) {
  __shared__ __bf16 As[2][128 * 32];
  __shared__ __bf16 Bs[2][128 * 32];

  const int tid = threadIdx.x;
  const int wid = tid >> 6;
  const int lane = tid & 63;
  const int l15 = lane & 15;
  const int quad = lane >> 4;
  const int bm = blockIdx.y * 128;
  const int bn = blockIdx.x * 128;
  const int wm = (wid & 1) * 64;
  const int wn = (wid >> 1) * 64;

  // staging: lane l -> row wid*16+(l>>2), global chunk (l&3)^((l>>3)&3)
  const int srow = wid * 16 + (lane >> 2);
  const int schunk = ((lane & 3) ^ ((lane >> 3) & 3)) * 8;
  const __bf16* gA = A + (size_t)(bm + srow) * K + schunk;
  const __bf16* gB = B + (size_t)(bn + srow) * K + schunk;
  const int ldsoff = wid * 16 * 32;  // wave-uniform

  // fragment-read chunk slot (loop-invariant; wm/i*16 vanish mod 4 after >>1)
  const int fsl = (quad ^ ((l15 >> 1) & 3)) * 8;

  f32x4 acc[4][4] = {};

  load_lds16(gA, &As[0][ldsoff]);
  load_lds16(gA + (size_t)64 * K, &As[0][64 * 32 + ldsoff]);
  load_lds16(gB, &Bs[0][ldsoff]);
  load_lds16(gB + (size_t)64 * K, &Bs[0][64 * 32 + ldsoff]);

  const int niter = K >> 5;
  for (int it = 0; it < niter; ++it) {
    const int cur = it & 1;
    __syncthreads();
    if (it + 1 < niter) {
      int k0 = (it + 1) << 5;
      load_lds16(gA + k0, &As[1 - cur][ldsoff]);
      load_lds16(gA + k0 + (size_t)64 * K, &As[1 - cur][64 * 32 + ldsoff]);
      load_lds16(gB + k0, &Bs[1 - cur][ldsoff]);
      load_lds16(gB + k0 + (size_t)64 * K, &Bs[1 - cur][64 * 32 + ldsoff]);
    }
    bf16x8 af[4], bf[4];
#pragma unroll
    for (int i = 0; i < 4; ++i)
      af[i] = *(const bf16x8*)(&As[cur][(wm + i * 16 + l15) * 32 + fsl]);
#pragma unroll
    for (int i = 0; i < 4; ++i)
      bf[i] = *(const bf16x8*)(&Bs[cur][(wn + i * 16 + l15) * 32 + fsl]);
#pragma unroll
    for (int mt = 0; mt < 4; ++mt)
#pragma unroll
      for (int nt = 0; nt < 4; ++nt)
        acc[mt][nt] = mfma16(af[mt], bf[nt], acc[mt][nt]);
  }

  const float sc = (bn < qcols) ? 0.18033688011112043f : 1.0f;
#pragma unroll
  for (int mt = 0; mt < 4; ++mt) {
#pragma unroll
    for (int nt = 0; nt < 4; ++nt) {
      int gc = bn + wn + nt * 16 + l15;
      float bv = bias[gc];
#pragma unroll
      for (int r = 0; r < 4; ++r) {
        int gr = bm + wm + mt * 16 + quad * 4 + r;
        float val = (acc[mt][nt][r] + bv) * sc;
        if constexpr (C_BF16)
          ((__bf16*)Cv)[(size_t)gr * N + gc] = (__bf16)val;
        else
          ((float*)Cv)[(size_t)gr * N + gc] = val;
      }
    }
  }
}

// exp + (optional causal mask) + deferred-l + packed P store in pi-layout.
template <bool MASK>
__device__ __forceinline__ void softmax_block(f32x4 (&s)[2][4],
                                              float (&lsum)[2][4],
                                              __bf16* __restrict__ psw,
                                              int kv0, int qrow_base, int quad,
                                              int l15) {
#pragma unroll
  for (int mt = 0; mt < 2; ++mt) {
#pragma unroll
    for (int r = 0; r < 4; ++r) {
      int prow = mt * 16 + quad * 4 + r;
      float p[4];
#pragma unroll
      for (int nt = 0; nt < 4; ++nt) {
        p[nt] = fast_exp2(s[mt][nt][r]);  // scale pre-folded into Q
        if constexpr (MASK) {
          if ((kv0 + nt * 16 + l15) > (qrow_base + prow)) p[nt] = 0.f;
        }
      }
      lsum[mt][r] += (p[0] + p[1]) + (p[2] + p[3]);
      uint2 w = {pack_bf16(p[0], p[1]), pack_bf16(p[2], p[3])};
      int o = ((l15 >> 1) ^ (prow & 7)) & 7;
      *(uint2*)(psw + prow * 64 + o * 8 + 4 * (l15 & 1)) = w;
    }
  }
}

// Flash attention, causal. qkv: (B*T, 3072) bf16 (Q pre-scaled by log2e/8);
// out: (B*T, 1024) bf16. Grid (64 bh, 8 pb) bh-fastest. Block 256 = 4 waves,
// BQ=128, BKV=64; phases {pb, 15-pb} -> 34 tiles/block.
// EXACT r0 attn + T5 setprio on both MFMA clusters (the r4 config; setprio
// delta ~-2.8 us supported by r4's per-dispatch-measured QKV penalty).
// r8 cast doubt on the packed-butterfly out-store (cross-run subtraction
// noise, guide rule #13) -> scalar out-store restored. r7's write-behind
// regressed hard (occupancy 10.9%, 3.3M conflicts) -> classic staging.
__global__ __launch_bounds__(256) void attn_kernel(
    const __bf16* __restrict__ qkv, __bf16* __restrict__ out) {
  constexpr int T = 2048, C3 = 3072;
  constexpr int KVSTEP = 64 * C3;
  __shared__ __bf16 Ks[2][64 * 64];  // [kv][d]
  __shared__ __bf16 Vt[2][64 * 64];  // [d][pi(kv)]
  __shared__ __bf16 Ps[4][32 * 64];  // per-wave [qrow][pi(kv)]

  const int tid = threadIdx.x;
  const int wid = tid >> 6;
  const int lane = tid & 63;
  const int l15 = lane & 15;
  const int quad = lane >> 4;
  const int bh = blockIdx.x;  // 0..63 (fastest -> same XCD per bh)
  const int pb = blockIdx.y;  // 0..7
  const int b = bh >> 4, h = bh & 15;
  const size_t rowbase = (size_t)b * T;

  const int kr = tid >> 3;  // K staging: rows kr, kr+32
  const int kc = tid & 7;   // d-octet
  const int vj = tid >> 4;  // V staging: rows vj+16i -> pi-cols 4vj+i
  const int vn = tid & 15;  // d-nibble

  const __bf16* gk_base = qkv + rowbase * C3 + 1024 + h * 64 + kr * C3 + kc * 8;
  const __bf16* gv_base = qkv + rowbase * C3 + 2048 + h * 64 + vj * C3 + vn * 4;

  // ---- loop-invariant LDS offsets (elements) ----
  int ks_st0 = kr * 64 + ((kc ^ (kr & 7)) * 8);            // K store row kr
  int ks_st1 = (kr + 32) * 64 + ((kc ^ ((kr + 32) & 7)) * 8);
  int vt_st[4];
#pragma unroll
  for (int dd = 0; dd < 4; ++dd) {
    int d = 4 * vn + dd;
    vt_st[dd] = d * 64 + ((((vj >> 1) ^ (d & 7) ^ (d >> 3)) & 7) * 8) +
                4 * (vj & 1);
  }
  int kf_off[4][2];
#pragma unroll
  for (int nt = 0; nt < 4; ++nt)
#pragma unroll
    for (int ksi = 0; ksi < 2; ++ksi)
      kf_off[nt][ksi] =
          (nt * 16 + l15) * 64 + (((4 * ksi + quad) ^ (l15 & 7)) * 8);
  int pf_off[2][2];
#pragma unroll
  for (int mt = 0; mt < 2; ++mt)
#pragma unroll
    for (int ksi = 0; ksi < 2; ++ksi)
      pf_off[mt][ksi] =
          (mt * 16 + l15) * 64 + (((4 * ksi + quad) ^ (l15 & 7)) * 8);
  int vf_off[4][2];
#pragma unroll
  for (int ntv = 0; ntv < 4; ++ntv)
#pragma unroll
    for (int ksi = 0; ksi < 2; ++ksi) {
      int d = ntv * 16 + l15;
      vf_off[ntv][ksi] =
          d * 64 + ((((4 * ksi + quad) ^ (d & 7) ^ (d >> 3)) & 7) * 8);
    }

#pragma unroll 1
  for (int phase = 0; phase < 2; ++phase) {
    const int qp = phase == 0 ? pb : 15 - pb;
    const int q0 = qp * 128;
    const int ntiles = 2 * qp + 2;
    const int qrow_base = q0 + wid * 32;

    bf16x8 qf[2][2];
#pragma unroll
    for (int mt = 0; mt < 2; ++mt)
#pragma unroll
      for (int ksi = 0; ksi < 2; ++ksi)
        qf[mt][ksi] = *(const bf16x8*)(
            qkv + (rowbase + qrow_base + mt * 16 + l15) * C3 + h * 64 +
            ksi * 32 + quad * 8);

    f32x4 acc[2][4] = {};
    float lsum[2][4] = {};

    const __bf16* gk = gk_base;
    const __bf16* gv = gv_base;

    bf16x8 kreg[2];
    bf16x4 vreg[4];
    kreg[0] = *(const bf16x8*)(gk);
    kreg[1] = *(const bf16x8*)(gk + 32 * C3);
#pragma unroll
    for (int i = 0; i < 4; ++i)
      vreg[i] = *(const bf16x4*)(gv + i * 16 * C3);

    __syncthreads();  // previous phase's readers done

    for (int j = 0; j < ntiles; ++j) {
      __bf16* ksb = Ks[j & 1];
      __bf16* vtb = Vt[j & 1];
      *(bf16x8*)(ksb + ks_st0) = kreg[0];
      *(bf16x8*)(ksb + ks_st1) = kreg[1];
#pragma unroll
      for (int dd = 0; dd < 4; ++dd) {
        bf16x4 t = {vreg[0][dd], vreg[1][dd], vreg[2][dd], vreg[3][dd]};
        *(bf16x4*)(vtb + vt_st[dd]) = t;
      }
      if (j + 1 < ntiles) {
        gk += KVSTEP;
        gv += KVSTEP;
        kreg[0] = *(const bf16x8*)(gk);
        kreg[1] = *(const bf16x8*)(gk + 32 * C3);
#pragma unroll
        for (int i = 0; i < 4; ++i)
          vreg[i] = *(const bf16x4*)(gv + i * 16 * C3);
      }
      __syncthreads();

      const int kv0 = j * 64;
      // ---- S = Q K^T ----
      f32x4 s[2][4] = {};
      __builtin_amdgcn_s_setprio(1);
#pragma unroll
      for (int nt = 0; nt < 4; ++nt) {
#pragma unroll
        for (int ksi = 0; ksi < 2; ++ksi) {
          bf16x8 kf = *(const bf16x8*)(ksb + kf_off[nt][ksi]);
#pragma unroll
          for (int mt = 0; mt < 2; ++mt)
            s[mt][nt] = mfma16(qf[mt][ksi], kf, s[mt][nt]);
        }
      }
      __builtin_amdgcn_s_setprio(0);
      // ---- softmax (wave-uniform mask branch) ----
      if ((kv0 + 63) > qrow_base)
        softmax_block<true>(s, lsum, Ps[wid], kv0, qrow_base, quad, l15);
      else
        softmax_block<false>(s, lsum, Ps[wid], kv0, qrow_base, quad, l15);

      // ---- O += P V (per-wave Ps: no barrier) ----
      __builtin_amdgcn_s_setprio(1);
#pragma unroll
      for (int ksi = 0; ksi < 2; ++ksi) {
        bf16x8 pf[2];
#pragma unroll
        for (int mt = 0; mt < 2; ++mt)
          pf[mt] = *(const bf16x8*)(Ps[wid] + pf_off[mt][ksi]);
#pragma unroll
        for (int ntv = 0; ntv < 4; ++ntv) {
          bf16x8 vf = *(const bf16x8*)(vtb + vf_off[ntv][ksi]);
#pragma unroll
          for (int mt = 0; mt < 2; ++mt)
            acc[mt][ntv] = mfma16(pf[mt], vf, acc[mt][ntv]);
        }
      }
      __builtin_amdgcn_s_setprio(0);
    }

    // ---- phase epilogue: reduce l, normalize, store (r0 scalar form) ----
#pragma unroll
    for (int mt = 0; mt < 2; ++mt)
#pragma unroll
      for (int r = 0; r < 4; ++r) {
        float l = lsum[mt][r];
        l += __shfl_xor(l, 1);
        l += __shfl_xor(l, 2);
        l += __shfl_xor(l, 4);
        l += __shfl_xor(l, 8);
        float inv = 1.0f / l;
        int row = qrow_base + mt * 16 + quad * 4 + r;
        size_t ob = (rowbase + row) * 1024 + h * 64;
#pragma unroll
        for (int ntv = 0; ntv < 4; ++ntv)
          out[ob + ntv * 16 + l15] = (__bf16)(acc[mt][ntv][r] * inv);
      }
  }
}

extern "C" void kernel_launch(void* const* d_in, const int* in_sizes, int n_in,
                              void* d_out, int out_size, void* d_ws,
                              size_t ws_size, hipStream_t stream) {
  const float* x = (const float*)d_in[0];
  const float* qkv_w = (const float*)d_in[1];
  const float* qkv_b = (const float*)d_in[2];
  const float* out_w = (const float*)d_in[3];
  const float* out_b = (const float*)d_in[4];
  float* out = (float*)d_out;

  __bf16* qkv_ws = (__bf16*)d_ws;                  // 8192*3072
  __bf16* attn_ws = qkv_ws + (size_t)8192 * 3072;  // 8192*1024
  __bf16* xb = attn_ws + (size_t)8192 * 1024;      // 8192*1024
  __bf16* wqb = xb + (size_t)8192 * 1024;          // 3072*1024
  __bf16* wob = wqb + (size_t)3072 * 1024;         // 1024*1024

  convert3<<<6144, 256, 0, stream>>>(x, qkv_w, out_w, xb, wqb, wob);
  gemm_bt<true><<<dim3(24, 64), 256, 0, stream>>>(xb, wqb, qkv_b, qkv_ws,
                                                  8192, 3072, 1024, 1024);
  attn_kernel<<<dim3(64, 8), 256, 0, stream>>>(qkv_ws, attn_ws);
  gemm_bt<false><<<dim3(8, 64), 256, 0, stream>>>(attn_ws, wob, out_b, out,
                                                  8192, 1024, 1024, 0);
}